// Round 7
// baseline (121.449 us; speedup 1.0000x reference)
//
#include <hip/hip_runtime.h>

constexpr int K   = 49;    // 7x7 kernel flattened
constexpr int C   = 32;    // out channels
constexpr int BLK = 256;

// 4-byte-aligned float4 (row base w*196B is only dword-aligned).
typedef float v4 __attribute__((ext_vector_type(4), aligned(4)));

// Design: per-thread k-chunked streaming dot products.
//  - 3 runtime-loop chunks of 16 k (4 x dwordx4 loads + 512 FMAs each):
//    small VMEM bursts, latency hidden under previous chunk's FMAs.
//  - 32 accumulators in DISTINCT VGPRs until the final stores: no
//    store-source register reuse -> no vmcnt waits inside compute.
//  - no LDS, <=64 VGPR -> 8 waves/SIMD (32/CU) for latency hiding.
__global__ __launch_bounds__(BLK, 8) void conv2d_stream(
    const float* __restrict__ enc_x,
    const float* __restrict__ weight,   // [C*K] uniform -> scalar loads
    const float* __restrict__ bias,     // [C]
    float* __restrict__ out,            // [C * windows_nb]
    int windows_nb)
{
    const size_t w = (size_t)blockIdx.x * BLK + threadIdx.x;
    if (w >= (size_t)windows_nb) return;
    const float* __restrict__ row = enc_x + w * (size_t)K;

    // Tail element k=48 issued first: its latency hides under chunks 0-2.
    const float x48 = row[48];

    float acc[C];
#pragma unroll
    for (int c = 0; c < C; ++c) acc[c] = bias[c];

#pragma unroll 1                      // keep chunks sequential: small bursts
    for (int j = 0; j < 3; ++j) {     // k = 16j .. 16j+15
        v4 xv[4];
#pragma unroll
        for (int r = 0; r < 4; ++r)
            xv[r] = *reinterpret_cast<const v4*>(row + j * 16 + r * 4);

        const float* __restrict__ wj = weight + j * 16;   // uniform base
#pragma unroll
        for (int c = 0; c < C; ++c) {
            const float* __restrict__ wc = wj + c * K;    // consecutive 16 floats
#pragma unroll
            for (int r = 0; r < 4; ++r)
#pragma unroll
                for (int i = 0; i < 4; ++i)
                    acc[c] = fmaf(xv[r][i], wc[r * 4 + i], acc[c]);
        }
    }

    // k = 48 tail.
#pragma unroll
    for (int c = 0; c < C; ++c)
        acc[c] = fmaf(x48, weight[c * K + 48], acc[c]);

    // 32 stores, each from a distinct register, nothing redefined after:
    // no store-completion waits; wave retires while writes drain.
#pragma unroll
    for (int c = 0; c < C; ++c)
        out[(size_t)c * windows_nb + w] = acc[c];
}

extern "C" void kernel_launch(void* const* d_in, const int* in_sizes, int n_in,
                              void* d_out, int out_size, void* d_ws, size_t ws_size,
                              hipStream_t stream) {
    const float* enc_x  = (const float*)d_in[0];
    const float* weight = (const float*)d_in[1];   // [C,7,7] flat
    const float* bias   = (const float*)d_in[2];   // [C]
    float* out = (float*)d_out;

    const int windows_nb = in_sizes[0] / K;        // 1048576
    const int nblocks = (windows_nb + BLK - 1) / BLK;

    conv2d_stream<<<nblocks, BLK, 0, stream>>>(enc_x, weight, bias, out, windows_nb);
}